// Round 17
// baseline (90.698 us; speedup 1.0000x reference)
//
#include <hip/hip_runtime.h>
#include <math.h>

#define NPOS  32768      // B*H*W
#define CDIM  128
#define HS    64
#define WSZ   64

typedef __bf16 bf8_t  __attribute__((ext_vector_type(8)));
typedef float  f32x4  __attribute__((ext_vector_type(4)));

__device__ __forceinline__ float gelu_exact(float x) {
    return 0.5f * x * (1.0f + erff(x * 0.70710678118654752f));
}

__device__ __forceinline__ unsigned short bf16c(float v) {
    return __builtin_bit_cast(unsigned short, (__bf16)v);
}

__device__ __forceinline__ uint4 pack8hi(const float* v) {
    unsigned hh[8];
    #pragma unroll
    for (int i = 0; i < 8; ++i) hh[i] = (unsigned)bf16c(v[i]);
    return make_uint4(hh[0] | (hh[1] << 16), hh[2] | (hh[3] << 16),
                      hh[4] | (hh[5] << 16), hh[6] | (hh[7] << 16));
}

__device__ __forceinline__ float bfd(unsigned u) {        // low 16 bits as bf16
    return __builtin_bit_cast(float, u << 16);
}

// unpack uint4 (8 bf16) and fma into acc[8] with weight
__device__ __forceinline__ void ufma(float* acc, uint4 c, float wgt) {
    const unsigned* cc = (const unsigned*)&c;
    #pragma unroll
    for (int j = 0; j < 4; ++j) {
        acc[2 * j]     += __builtin_bit_cast(float, cc[j] << 16) * wgt;
        acc[2 * j + 1] += __builtin_bit_cast(float, cc[j] & 0xFFFF0000u) * wgt;
    }
}

// ---------------------------------------------------------------------------
// A-frag layouts (K=KC*32): hi-only buffers: block(rt,kc) = 512 ush
//  elem: lane*8 + i, lane = (row%16) + ((k%32)/8)*16, i = k%8
// ---------------------------------------------------------------------------

// ---------------------------------------------------------------------------
// prep body: blocks [0,130) border: zero 1-px ring of bf16 xpad
//            [130,184) wprep: weights -> frag bf16
// ---------------------------------------------------------------------------
__device__ void prep_body(
    int bid, int tid,
    unsigned short* __restrict__ xpad,
    const float* __restrict__ w0, const float* __restrict__ w1,
    const float* __restrict__ w2, const float* __restrict__ w3,
    const float* __restrict__ w4, unsigned short* __restrict__ wb)
{
    if (bid < 130) {
        int idx = bid * 256 + tid;         // 2080 cells * 16
        if (idx < 33280) {
            int c8 = (idx & 15) * 8;
            int cell = idx >> 4;
            int b = cell / 260, r = cell % 260;
            int h, w;
            if (r < 66)       { h = 0;  w = r; }
            else if (r < 132) { h = 65; w = r - 66; }
            else { int rr = r - 132; h = 1 + (rr >> 1); w = (rr & 1) * 65; }
            size_t o = (((size_t)b * 66 + h) * 66 + w) * 128 + c8;
            *(uint4*)(xpad + o) = make_uint4(0u, 0u, 0u, 0u);
        }
    } else {
        int sub = (bid - 130) * 4 + (tid >> 6);    // 0..215
        int lane = tid & 63;
        int NT, K, local; unsigned short* out; bool hl; bool comb = false;
        const float* W = nullptr; int N = 0;
        if (sub < 32)       { NT = 8;  K = 128; out = wb;          local = sub;       hl = false; W = w0; N = 128; }
        else if (sub < 88)  { NT = 14; K = 128; out = wb + 16384;  local = sub - 32;  hl = false; comb = true; }
        else if (sub < 152) { NT = 16; K = 128; out = wb + 45056;  local = sub - 88;  hl = true;  W = w3; N = 256; }
        else                { NT = 8;  K = 256; out = wb + 110592; local = sub - 152; hl = true;  W = w4; N = 128; }
        int KC = K / 32;
        int unit = KC * NT * 512;
        int kc = local / NT, t = local % NT;
        int nt = t * 16 + (lane & 15);
        const float* Wp = W; int n = nt, Nv = N;
        if (comb) {
            if (t < 9) { Wp = w1; n = nt;       Nv = 144; }
            else       { Wp = w2; n = nt - 144; Nv = 72;  }
        }
        int kb = kc * 32 + (lane >> 4) * 8;
        size_t base = ((size_t)local * 64 + lane) * 8;
        #pragma unroll
        for (int i = 0; i < 8; ++i) {
            float v = (n < Nv) ? Wp[(size_t)n * K + kb + i] : 0.f;
            __bf16 h = (__bf16)v;
            out[base + i] = __builtin_bit_cast(unsigned short, h);
            if (hl) {
                __bf16 l = (__bf16)(v - (float)h);
                out[unit + base + i] = __builtin_bit_cast(unsigned short, l);
            }
        }
    }
}

// ---------------------------------------------------------------------------
// dwconv body: depthwise 3x3 (NHWC) -> bf16 ydw + partial BN sums (fp32)
//              + center-tap -> inpf hi-only frags (folded aprep)
// ---------------------------------------------------------------------------
__device__ void dwconv_body(
    int blk, int tid,
    const float* __restrict__ inp, const float* __restrict__ dww,
    const float* __restrict__ dwb, unsigned short* __restrict__ ydwb,
    float* __restrict__ psum, float* __restrict__ psq,
    unsigned short* __restrict__ inpf)
{
    int b = blk >> 6, h = blk & 63;
    int c4 = (tid & 31) * 4;
    int wg = tid >> 5;               // 0..7

    float wreg[4][9];
    #pragma unroll
    for (int cc = 0; cc < 4; ++cc)
        #pragma unroll
        for (int p = 0; p < 9; ++p)
            wreg[cc][p] = dww[(c4 + cc) * 9 + p];
    float bia[4];
    #pragma unroll
    for (int cc = 0; cc < 4; ++cc) bia[cc] = dwb[c4 + cc];

    float s4[4] = {0,0,0,0}, q4[4] = {0,0,0,0};
    const float* ibase = inp + (size_t)(b << 12) * CDIM;

    for (int i = 0; i < 8; ++i) {
        int w = wg + i * 8;
        float acc[4] = {bia[0], bia[1], bia[2], bia[3]};
        float4 ctr;
        #pragma unroll
        for (int ky = 0; ky < 3; ++ky) {
            int yy = h + ky - 1;
            if (yy < 0 || yy >= HS) continue;
            #pragma unroll
            for (int kx = 0; kx < 3; ++kx) {
                int xx = w + kx - 1;
                if (xx < 0 || xx >= WSZ) continue;
                float4 v = *(const float4*)(ibase + (size_t)(yy * 64 + xx) * CDIM + c4);
                if (ky == 1 && kx == 1) ctr = v;
                int p = ky * 3 + kx;
                acc[0] += v.x * wreg[0][p];
                acc[1] += v.y * wreg[1][p];
                acc[2] += v.z * wreg[2][p];
                acc[3] += v.w * wreg[3][p];
            }
        }
        int r = (b << 12) + h * 64 + w;
        ushort4 o;
        o.x = bf16c(acc[0]); o.y = bf16c(acc[1]);
        o.z = bf16c(acc[2]); o.w = bf16c(acc[3]);
        *(ushort4*)(ydwb + (size_t)r * CDIM + c4) = o;
        // folded aprep: center tap -> inpf hi-only frag (4 channels)
        {
            int rt = r >> 4, kc = c4 >> 5;
            int lp = (r & 15) + ((c4 & 31) >> 3) * 16;
            int i0 = c4 & 7;
            unsigned u0 = (unsigned)bf16c(ctr.x) | ((unsigned)bf16c(ctr.y) << 16);
            unsigned u1 = (unsigned)bf16c(ctr.z) | ((unsigned)bf16c(ctr.w) << 16);
            *(uint2*)(inpf + ((size_t)rt * 4 + kc) * 512 + lp * 8 + i0) = make_uint2(u0, u1);
        }
        #pragma unroll
        for (int cc = 0; cc < 4; ++cc) { s4[cc] += acc[cc]; q4[cc] += acc[cc] * acc[cc]; }
    }

    __shared__ float ls[8][128], lq[8][128];
    #pragma unroll
    for (int cc = 0; cc < 4; ++cc) { ls[wg][c4 + cc] = s4[cc]; lq[wg][c4 + cc] = q4[cc]; }
    __syncthreads();
    if (tid < 128) {
        float s = 0.f, q = 0.f;
        #pragma unroll
        for (int r = 0; r < 8; ++r) { s += ls[r][tid]; q += lq[r][tid]; }
        psum[blk * 128 + tid] = s;
        psq [blk * 128 + tid] = q;
    }
}

// K_pd: merged prep (184 blocks) + dwconv (512 blocks). grid 696.
__global__ __launch_bounds__(256) void k_pd(
    const float* __restrict__ inp, unsigned short* __restrict__ inpf,
    unsigned short* __restrict__ xpad,
    const float* __restrict__ w0, const float* __restrict__ w1,
    const float* __restrict__ w2, const float* __restrict__ w3,
    const float* __restrict__ w4, unsigned short* __restrict__ wb,
    const float* __restrict__ dww, const float* __restrict__ dwb,
    unsigned short* __restrict__ ydwb, float* __restrict__ psum,
    float* __restrict__ psq)
{
    int bid = blockIdx.x;
    if (bid < 184) prep_body(bid, threadIdx.x, xpad, w0, w1, w2, w3, w4, wb);
    else           dwconv_body(bid - 184, threadIdx.x, inp, dww, dwb, ydwb, psum, psq, inpf);
}

// ---------------------------------------------------------------------------
// K2: finalize BN stats -> scale/shift per channel.
// ---------------------------------------------------------------------------
__global__ __launch_bounds__(256) void k_bnstats(
    const float* __restrict__ psum, const float* __restrict__ psq,
    const float* __restrict__ gamma, const float* __restrict__ beta,
    float* __restrict__ sc, float* __restrict__ sh)
{
    int c = blockIdx.x;
    int t = threadIdx.x;
    float s = psum[t * 128 + c] + psum[(t + 256) * 128 + c];
    float q = psq [t * 128 + c] + psq [(t + 256) * 128 + c];
    __shared__ float rs[256], rq[256];
    rs[t] = s; rq[t] = q; __syncthreads();
    for (int off = 128; off > 0; off >>= 1) {
        if (t < off) { rs[t] += rs[t + off]; rq[t] += rq[t + off]; }
        __syncthreads();
    }
    if (t == 0) {
        float mean = rs[0] * (1.0f / 32768.0f);
        float var  = rq[0] * (1.0f / 32768.0f) - mean * mean;
        float scale = gamma[c] * rsqrtf(var + 1e-5f);
        sc[c] = scale;
        sh[c] = beta[c] - mean * scale;
    }
}

// ---------------------------------------------------------------------------
// bngelu body: bf16 ydw -> BN + exact GELU -> x1 hi-only frags.
// ---------------------------------------------------------------------------
__device__ void bngelu_body(
    int bid, int tid,
    const unsigned short* __restrict__ ydwb, const float* __restrict__ sc,
    const float* __restrict__ sh, unsigned short* __restrict__ dst)
{
    int idx = bid * 256 + tid;   // 32768*16
    int r = idx >> 4, k8 = (idx & 15) * 8;
    uint4 yv = *(const uint4*)(ydwb + (size_t)r * 128 + k8);
    const unsigned* cc = (const unsigned*)&yv;
    float t[8];
    #pragma unroll
    for (int j = 0; j < 4; ++j) {
        t[2 * j]     = bfd(cc[j]);
        t[2 * j + 1] = __builtin_bit_cast(float, cc[j] & 0xFFFF0000u);
    }
    float s[8], h[8];
    *(float4*)(s)     = *(const float4*)(sc + k8);
    *(float4*)(s + 4) = *(const float4*)(sc + k8 + 4);
    *(float4*)(h)     = *(const float4*)(sh + k8);
    *(float4*)(h + 4) = *(const float4*)(sh + k8 + 4);
    #pragma unroll
    for (int i = 0; i < 8; ++i) t[i] = gelu_exact(t[i] * s[i] + h[i]);
    uint4 hi = pack8hi(t);
    int rt = r >> 4, kc = k8 >> 5, lp = (r & 15) + ((k8 & 31) >> 3) * 16;
    size_t base = ((size_t)rt * 4 + kc) * 512 + lp * 8;
    *(uint4*)(dst + base) = hi;
}

// ---------------------------------------------------------------------------
// Frag-stream MFMA GEMM body (hi-only). MODE 3: bf16 padded store.
// ---------------------------------------------------------------------------
template<int KDIM, int NT_TOT, int NT_W, int MODE, int NV>
__device__ void fgemm_body(
    int bx, int by, int tid,
    const unsigned short* __restrict__ AF, const unsigned short* __restrict__ WF,
    const float* __restrict__ bias, float* __restrict__ C)
{
    constexpr int KC = KDIM / 32;
    int lane = tid & 63, w = tid >> 6;
    int rt0 = bx * 8 + w * 2;      // 2 rowtiles per wave
    int t0 = by * NT_W;            // n-tile chunk base

    f32x4 acc[2][NT_W];
    #pragma unroll
    for (int rt = 0; rt < 2; ++rt)
        #pragma unroll
        for (int t = 0; t < NT_W; ++t) acc[rt][t] = (f32x4){0.f, 0.f, 0.f, 0.f};

    const bf8_t* Ab0 = (const bf8_t*)AF + (size_t)rt0 * KC * 64 + lane;
    const bf8_t* Ab1 = Ab0 + KC * 64;
    const bf8_t* WHp = (const bf8_t*)WF + lane;

    #pragma unroll
    for (int kc = 0; kc < KC; ++kc) {
        bf8_t a0h = Ab0[kc * 64];
        bf8_t a1h = Ab1[kc * 64];
        #pragma unroll
        for (int t = 0; t < NT_W; ++t) {
            int tg = t0 + t;
            if (tg < NT_TOT) {
                bf8_t wh = WHp[(kc * NT_TOT + tg) * 64];
                acc[0][t] = __builtin_amdgcn_mfma_f32_16x16x32_bf16(wh, a0h, acc[0][t], 0, 0, 0);
                acc[1][t] = __builtin_amdgcn_mfma_f32_16x16x32_bf16(wh, a1h, acc[1][t], 0, 0, 0);
            }
        }
    }

    #pragma unroll
    for (int rt = 0; rt < 2; ++rt) {
        if (MODE == 3) {
            unsigned short* Cp = (unsigned short*)C;
            int m = (rt0 + rt) * 16 + (lane & 15);
            int bb_ = m >> 12, hwm = m & 4095;
            size_t rowb = (((size_t)bb_ * 66 + (hwm >> 6) + 1) * 66 + (hwm & 63) + 1) * 128;
            #pragma unroll
            for (int t = 0; t < NT_W; ++t) {
                int tg = t0 + t;
                int nb = tg * 16 + ((lane >> 4) << 2);
                if (tg < NT_TOT) {
                    float4 bb = *(const float4*)(bias + nb);
                    f32x4 a = acc[rt][t];
                    ushort4 v;
                    v.x = bf16c(a[0] + bb.x); v.y = bf16c(a[1] + bb.y);
                    v.z = bf16c(a[2] + bb.z); v.w = bf16c(a[3] + bb.w);
                    *(ushort4*)(Cp + rowb + nb) = v;
                }
            }
        }
    }
}

// K_bp: merged bngelu (2048 blocks) + proj GEMM (512 blocks, NT_W=4). grid 2560.
__global__ __launch_bounds__(256) void k_bp(
    const unsigned short* __restrict__ ydwb, const float* __restrict__ sc,
    const float* __restrict__ sh, unsigned short* __restrict__ x1f,
    const unsigned short* __restrict__ inpf, const unsigned short* __restrict__ wprojf,
    const float* __restrict__ bproj, unsigned short* __restrict__ xpad)
{
    int bid = blockIdx.x;
    if (bid < 2048) {
        bngelu_body(bid, threadIdx.x, ydwb, sc, sh, x1f);
    } else {
        int pbid = bid - 2048;
        fgemm_body<128, 8, 4, 3, 128>(pbid & 255, pbid >> 8, threadIdx.x,
            inpf, wprojf, bproj, (float*)xpad);
    }
}

// ---------------------------------------------------------------------------
// K_dm: FUSED offset/mask GEMM + DCNv3 gather + output MLP.
// block = 512 threads (8 waves), 32 positions (= 2 rowtiles). grid 1024.
// Phase A: womb GEMM -> bias-added bf16 offs/msk in LDS (rounding identical
//          to old global store).
// Phase B: softmax + bilinear gather, thread = (pos,g,half); bf16 dcn frags
//          -> LDS dcn_l (pack8hi, identical rounding to old dcnf store).
// Phase C: fc1 from dcn_l A-frags (hi-only W) -> GELU -> bf16 hid in LDS
//          (hid reuses offs/msk LDS region, barrier-separated).
// Phase D: fc2 from hid A-frags (hi-only W) -> fp32 NCHW store.
// All rounding points identical to the previous 2-kernel path.
// ---------------------------------------------------------------------------
__global__ __launch_bounds__(512) void k_dm(
    const unsigned short* __restrict__ x1f, const unsigned short* __restrict__ womb,
    const float* __restrict__ boff, const float* __restrict__ bmask,
    const unsigned short* __restrict__ xpad,
    const unsigned short* __restrict__ wf1, const float* __restrict__ bfc1,
    const unsigned short* __restrict__ wf2, const float* __restrict__ bfc2,
    float* __restrict__ out)
{
    __shared__ unsigned short hid[2][16][264];    // 16896 B; also hosts offs/msk in A/B
    __shared__ unsigned short dcn_l[2][16][136];  // 8704 B
    unsigned short (*offs_l)[148] = (unsigned short (*)[148])(&hid[0][0][0]);          // 32x148
    unsigned short (*msk_l)[76]   = (unsigned short (*)[76])(&hid[0][0][0] + 4736);    // 32x76

    int tid = threadIdx.x;
    int lane = tid & 63, wv = tid >> 6;          // 8 waves
    int rtl = wv & 1, chunk = wv >> 1;           // rowtile-local, chunk 0..3
    int rt = blockIdx.x * 2 + rtl;
    int m = lane & 15, hi4 = (lane >> 4) << 2;

    // ---- phase A: offs/msk GEMM into LDS ----
    {
        f32x4 acc[4];
        #pragma unroll
        for (int t = 0; t < 4; ++t) acc[t] = (f32x4){0.f, 0.f, 0.f, 0.f};
        const bf8_t* Ab = (const bf8_t*)x1f + (size_t)rt * 4 * 64 + lane;
        const bf8_t* WH = (const bf8_t*)womb + lane;
        #pragma unroll
        for (int kc = 0; kc < 4; ++kc) {
            bf8_t ah = Ab[kc * 64];
            #pragma unroll
            for (int t = 0; t < 4; ++t) {
                int tg = chunk * 4 + t;
                if (tg < 14) {
                    bf8_t wh = WH[(kc * 14 + tg) * 64];
                    acc[t] = __builtin_amdgcn_mfma_f32_16x16x32_bf16(wh, ah, acc[t], 0, 0, 0);
                }
            }
        }
        int ml = rtl * 16 + m;                   // local row 0..31
        #pragma unroll
        for (int t = 0; t < 4; ++t) {
            int tg = chunk * 4 + t;
            if (tg < 14) {
                int nb = tg * 16 + hi4;
                f32x4 a = acc[t];
                if (nb < 144) {
                    float4 bb = *(const float4*)(boff + nb);
                    ushort4 v;
                    v.x = bf16c(a[0] + bb.x); v.y = bf16c(a[1] + bb.y);
                    v.z = bf16c(a[2] + bb.z); v.w = bf16c(a[3] + bb.w);
                    *(ushort4*)(&offs_l[ml][nb]) = v;
                } else {
                    int col = nb - 144;
                    if (col + 4 <= 72) {
                        float4 bb = *(const float4*)(bmask + col);
                        ushort4 v;
                        v.x = bf16c(a[0] + bb.x); v.y = bf16c(a[1] + bb.y);
                        v.z = bf16c(a[2] + bb.z); v.w = bf16c(a[3] + bb.w);
                        *(ushort4*)(&msk_l[ml][col]) = v;
                    }
                }
            }
        }
    }
    __syncthreads();

    // ---- phase B: softmax + bilinear gather -> dcn frags in LDS ----
    {
        int q = tid & 1;
        int g = (tid >> 1) & 7;
        int lpos = tid >> 4;                     // 0..31
        int pos = blockIdx.x * 32 + lpos;
        int b = pos >> 12, hw = pos & 4095, h = hw >> 6, w = hw & 63;

        float e[9];
        float mx = -1e30f;
        #pragma unroll
        for (int p = 0; p < 9; ++p) { e[p] = bfd((unsigned)msk_l[lpos][g * 9 + p]); mx = fmaxf(mx, e[p]); }
        float ssum = 0.f;
        #pragma unroll
        for (int p = 0; p < 9; ++p) { e[p] = __expf(e[p] - mx); ssum += e[p]; }
        float inv = 1.0f / ssum;

        int ch = g * 16 + q * 8;
        const unsigned short* xb = xpad + (size_t)b * 557568 + ch;  // 66*66*128/b

        float acc[8];
        #pragma unroll
        for (int i = 0; i < 8; ++i) acc[i] = 0.f;

        #pragma unroll
        for (int p = 0; p < 9; ++p) {
            unsigned dpair = *(const unsigned*)(&offs_l[lpos][g * 18 + p * 2]);
            float dx = bfd(dpair);
            float dy = __builtin_bit_cast(float, dpair & 0xFFFF0000u);
            float px = (float)(w + (p % 3)) + dx;   // padded-grid coords
            float py = (float)(h + (p / 3)) + dy;
            float x0f = floorf(px), y0f = floorf(py);
            float wx = px - x0f, wy = py - y0f;
            int ix = (int)x0f, iy = (int)y0f;
            int ix0 = max(min(ix, 65), 0),     ix1 = max(min(ix + 1, 65), 0);
            int iy0 = max(min(iy, 65), 0),     iy1 = max(min(iy + 1, 65), 0);
            int r0 = iy0 * 66, r1 = iy1 * 66;

            float mp  = e[p] * inv;
            float w11 = wy * wx * mp;
            float w10 = wy * mp - w11;
            float w01 = wx * mp - w11;
            float w00 = mp - w01 - w10 - w11;

            uint4 s00 = *(const uint4*)(xb + (size_t)(r0 + ix0) * 128);
            uint4 s01 = *(const uint4*)(xb + (size_t)(r0 + ix1) * 128);
            uint4 s10 = *(const uint4*)(xb + (size_t)(r1 + ix0) * 128);
            uint4 s11 = *(const uint4*)(xb + (size_t)(r1 + ix1) * 128);

            ufma(acc, s00, w00);
            ufma(acc, s01, w01);
            ufma(acc, s10, w10);
            ufma(acc, s11, w11);
        }

        // bf16 dcn frag (identical rounding to old dcnf store)
        *(uint4*)(&dcn_l[lpos >> 4][lpos & 15][ch]) = pack8hi(acc);
    }
    __syncthreads();   // also makes hid region (offs/msk) dead -> reusable

    // ---- phase C: fc1 (hidden tiles chunk*4..+3 for rowtile rtl) ----
    {
        f32x4 acc[4];
        #pragma unroll
        for (int t = 0; t < 4; ++t) acc[t] = (f32x4){0.f, 0.f, 0.f, 0.f};
        const bf8_t* WH1 = (const bf8_t*)wf1 + lane;
        #pragma unroll
        for (int kc = 0; kc < 4; ++kc) {
            bf8_t ah = *(const bf8_t*)(&dcn_l[rtl][m][kc * 32 + (lane >> 4) * 8]);
            #pragma unroll
            for (int t = 0; t < 4; ++t) {
                int tg = chunk * 4 + t;
                bf8_t wh = WH1[(kc * 16 + tg) * 64];
                acc[t] = __builtin_amdgcn_mfma_f32_16x16x32_bf16(wh, ah, acc[t], 0, 0, 0);
            }
        }
        #pragma unroll
        for (int t = 0; t < 4; ++t) {
            int nb = (chunk * 4 + t) * 16 + hi4;
            float4 bb = *(const float4*)(bfc1 + nb);
            ushort4 v;
            v.x = bf16c(gelu_exact(acc[t][0] + bb.x));
            v.y = bf16c(gelu_exact(acc[t][1] + bb.y));
            v.z = bf16c(gelu_exact(acc[t][2] + bb.z));
            v.w = bf16c(gelu_exact(acc[t][3] + bb.w));
            *(ushort4*)(&hid[rtl][m][nb]) = v;
        }
    }
    __syncthreads();

    // ---- phase D: fc2 (out tiles chunk*2..+1 for rowtile rtl) ----
    {
        f32x4 acc2[2];
        #pragma unroll
        for (int t = 0; t < 2; ++t) acc2[t] = (f32x4){0.f, 0.f, 0.f, 0.f};
        const bf8_t* WH2 = (const bf8_t*)wf2 + lane;
        #pragma unroll
        for (int kc = 0; kc < 8; ++kc) {
            bf8_t ah = *(const bf8_t*)(&hid[rtl][m][kc * 32 + (lane >> 4) * 8]);
            #pragma unroll
            for (int t = 0; t < 2; ++t) {
                int tg = chunk * 2 + t;
                bf8_t wh = WH2[(kc * 8 + tg) * 64];
                acc2[t] = __builtin_amdgcn_mfma_f32_16x16x32_bf16(ah, wh, acc2[t], 0, 0, 0);
            }
        }
        int m4 = rt * 16 + hi4;
        int b = m4 >> 12, hw = m4 & 4095;
        #pragma unroll
        for (int t = 0; t < 2; ++t) {
            int n = (chunk * 2 + t) * 16 + m;
            float bb = bfc2[n];
            f32x4 a = acc2[t];
            float4 v = {a[0] + bb, a[1] + bb, a[2] + bb, a[3] + bb};
            *(float4*)(out + (((size_t)(b * 128 + n)) << 12) + hw) = v;
        }
    }
}

// ---------------------------------------------------------------------------
extern "C" void kernel_launch(void* const* d_in, const int* in_sizes, int n_in,
                              void* d_out, int out_size, void* d_ws, size_t ws_size,
                              hipStream_t stream)
{
    const float* inp   = (const float*)d_in[0];
    const float* wproj = (const float*)d_in[1];
    const float* bproj = (const float*)d_in[2];
    const float* dww   = (const float*)d_in[3];
    const float* dwb   = (const float*)d_in[4];
    const float* gamma = (const float*)d_in[5];
    const float* beta  = (const float*)d_in[6];
    const float* woff  = (const float*)d_in[7];
    const float* boff  = (const float*)d_in[8];
    const float* wmask = (const float*)d_in[9];
    const float* bmask = (const float*)d_in[10];
    const float* wfc1  = (const float*)d_in[11];
    const float* bfc1  = (const float*)d_in[12];
    const float* wfc2  = (const float*)d_in[13];
    const float* bfc2  = (const float*)d_in[14];
    float* out = (float*)d_out;
    float* ws  = (float*)d_ws;

    // xpad (bf16)
    unsigned short* xpad = (unsigned short*)ws;              // 4,460,544 ush [bp..dm]
    // Region A at ws+9179136: inpf [pd..bp-proj]
    unsigned short* inpf  = (unsigned short*)(ws + 9179136);   // 4,194,304 ush hi-only
    unsigned short* x1f   = (unsigned short*)(ws + 13373440);  // 4,194,304 ush hi-only [bp..dm]
    unsigned short* ydwb  = (unsigned short*)(ws + 15470592);  // 4,194,304 ush bf16 [pd..bp]
    // Rest
    float* psum = ws + 19927040;                         // 65,536 f
    float* psq  = ws + 19992576;                         // 65,536 f
    float* scs  = ws + 20058112;                         // 128 f
    float* shs  = ws + 20058240;                         // 128 f
    unsigned short* wfr = (unsigned short*)(ws + 20058368);  // 176,128 ush

    unsigned short* wproj_f = wfr;            // hi-only, 16384
    unsigned short* womb_f  = wfr + 16384;    // hi-only combined, 28672
    unsigned short* wfc1_f  = wfr + 45056;    // hi(/lo stored), hi consumed
    unsigned short* wfc2_f  = wfr + 110592;   // hi(/lo stored), hi consumed

    k_pd<<<696, 256, 0, stream>>>(inp, inpf, xpad, wproj, woff, wmask, wfc1, wfc2,
                                  wfr, dww, dwb, ydwb, psum, psq);
    k_bnstats<<<128, 256, 0, stream>>>(psum, psq, gamma, beta, scs, shs);
    k_bp<<<2560, 256, 0, stream>>>(ydwb, scs, shs, x1f, inpf, wproj_f, bproj, xpad);
    k_dm<<<1024, 512, 0, stream>>>(x1f, womb_f, boff, bmask, xpad,
                                   wfc1_f, bfc1, wfc2_f, bfc2, out);
}

// Round 18
// 82.344 us; speedup vs baseline: 1.1015x; 1.1015x over previous
//
#include <hip/hip_runtime.h>
#include <math.h>

#define NPOS  32768      // B*H*W
#define CDIM  128
#define HS    64
#define WSZ   64

typedef __bf16 bf8_t  __attribute__((ext_vector_type(8)));
typedef float  f32x4  __attribute__((ext_vector_type(4)));

__device__ __forceinline__ float gelu_exact(float x) {
    return 0.5f * x * (1.0f + erff(x * 0.70710678118654752f));
}

__device__ __forceinline__ unsigned short bf16c(float v) {
    return __builtin_bit_cast(unsigned short, (__bf16)v);
}

__device__ __forceinline__ uint4 pack8hi(const float* v) {
    unsigned hh[8];
    #pragma unroll
    for (int i = 0; i < 8; ++i) hh[i] = (unsigned)bf16c(v[i]);
    return make_uint4(hh[0] | (hh[1] << 16), hh[2] | (hh[3] << 16),
                      hh[4] | (hh[5] << 16), hh[6] | (hh[7] << 16));
}

__device__ __forceinline__ float bfd(unsigned u) {        // low 16 bits as bf16
    return __builtin_bit_cast(float, u << 16);
}

// unpack uint4 (8 bf16) and fma into acc[8] with weight
__device__ __forceinline__ void ufma(float* acc, uint4 c, float wgt) {
    const unsigned* cc = (const unsigned*)&c;
    #pragma unroll
    for (int j = 0; j < 4; ++j) {
        acc[2 * j]     += __builtin_bit_cast(float, cc[j] << 16) * wgt;
        acc[2 * j + 1] += __builtin_bit_cast(float, cc[j] & 0xFFFF0000u) * wgt;
    }
}

// ---------------------------------------------------------------------------
// A-frag layouts (K=KC*32): hi-only buffers: block(rt,kc) = 512 ush
//  elem: lane*8 + i, lane = (row%16) + ((k%32)/8)*16, i = k%8
// ---------------------------------------------------------------------------

// ---------------------------------------------------------------------------
// prep body: blocks [0,130) border: zero 1-px ring of bf16 xpad
//            [130,184) wprep: weights -> frag bf16
// ---------------------------------------------------------------------------
__device__ void prep_body(
    int bid, int tid,
    unsigned short* __restrict__ xpad,
    const float* __restrict__ w0, const float* __restrict__ w1,
    const float* __restrict__ w2, const float* __restrict__ w3,
    const float* __restrict__ w4, unsigned short* __restrict__ wb)
{
    if (bid < 130) {
        int idx = bid * 256 + tid;         // 2080 cells * 16
        if (idx < 33280) {
            int c8 = (idx & 15) * 8;
            int cell = idx >> 4;
            int b = cell / 260, r = cell % 260;
            int h, w;
            if (r < 66)       { h = 0;  w = r; }
            else if (r < 132) { h = 65; w = r - 66; }
            else { int rr = r - 132; h = 1 + (rr >> 1); w = (rr & 1) * 65; }
            size_t o = (((size_t)b * 66 + h) * 66 + w) * 128 + c8;
            *(uint4*)(xpad + o) = make_uint4(0u, 0u, 0u, 0u);
        }
    } else {
        int sub = (bid - 130) * 4 + (tid >> 6);    // 0..215
        int lane = tid & 63;
        int NT, K, local; unsigned short* out; bool hl; bool comb = false;
        const float* W = nullptr; int N = 0;
        if (sub < 32)       { NT = 8;  K = 128; out = wb;          local = sub;       hl = false; W = w0; N = 128; }
        else if (sub < 88)  { NT = 14; K = 128; out = wb + 16384;  local = sub - 32;  hl = false; comb = true; }
        else if (sub < 152) { NT = 16; K = 128; out = wb + 45056;  local = sub - 88;  hl = true;  W = w3; N = 256; }
        else                { NT = 8;  K = 256; out = wb + 110592; local = sub - 152; hl = true;  W = w4; N = 128; }
        int KC = K / 32;
        int unit = KC * NT * 512;
        int kc = local / NT, t = local % NT;
        int nt = t * 16 + (lane & 15);
        const float* Wp = W; int n = nt, Nv = N;
        if (comb) {
            if (t < 9) { Wp = w1; n = nt;       Nv = 144; }
            else       { Wp = w2; n = nt - 144; Nv = 72;  }
        }
        int kb = kc * 32 + (lane >> 4) * 8;
        size_t base = ((size_t)local * 64 + lane) * 8;
        #pragma unroll
        for (int i = 0; i < 8; ++i) {
            float v = (n < Nv) ? Wp[(size_t)n * K + kb + i] : 0.f;
            __bf16 h = (__bf16)v;
            out[base + i] = __builtin_bit_cast(unsigned short, h);
            if (hl) {
                __bf16 l = (__bf16)(v - (float)h);
                out[unit + base + i] = __builtin_bit_cast(unsigned short, l);
            }
        }
    }
}

// ---------------------------------------------------------------------------
// dwconv body: depthwise 3x3 (NHWC) -> bf16 ydw + partial BN sums (fp32)
//              + center-tap -> inpf hi-only frags (folded aprep)
// ---------------------------------------------------------------------------
__device__ void dwconv_body(
    int blk, int tid,
    const float* __restrict__ inp, const float* __restrict__ dww,
    const float* __restrict__ dwb, unsigned short* __restrict__ ydwb,
    float* __restrict__ psum, float* __restrict__ psq,
    unsigned short* __restrict__ inpf)
{
    int b = blk >> 6, h = blk & 63;
    int c4 = (tid & 31) * 4;
    int wg = tid >> 5;               // 0..7

    float wreg[4][9];
    #pragma unroll
    for (int cc = 0; cc < 4; ++cc)
        #pragma unroll
        for (int p = 0; p < 9; ++p)
            wreg[cc][p] = dww[(c4 + cc) * 9 + p];
    float bia[4];
    #pragma unroll
    for (int cc = 0; cc < 4; ++cc) bia[cc] = dwb[c4 + cc];

    float s4[4] = {0,0,0,0}, q4[4] = {0,0,0,0};
    const float* ibase = inp + (size_t)(b << 12) * CDIM;

    for (int i = 0; i < 8; ++i) {
        int w = wg + i * 8;
        float acc[4] = {bia[0], bia[1], bia[2], bia[3]};
        float4 ctr;
        #pragma unroll
        for (int ky = 0; ky < 3; ++ky) {
            int yy = h + ky - 1;
            if (yy < 0 || yy >= HS) continue;
            #pragma unroll
            for (int kx = 0; kx < 3; ++kx) {
                int xx = w + kx - 1;
                if (xx < 0 || xx >= WSZ) continue;
                float4 v = *(const float4*)(ibase + (size_t)(yy * 64 + xx) * CDIM + c4);
                if (ky == 1 && kx == 1) ctr = v;
                int p = ky * 3 + kx;
                acc[0] += v.x * wreg[0][p];
                acc[1] += v.y * wreg[1][p];
                acc[2] += v.z * wreg[2][p];
                acc[3] += v.w * wreg[3][p];
            }
        }
        int r = (b << 12) + h * 64 + w;
        ushort4 o;
        o.x = bf16c(acc[0]); o.y = bf16c(acc[1]);
        o.z = bf16c(acc[2]); o.w = bf16c(acc[3]);
        *(ushort4*)(ydwb + (size_t)r * CDIM + c4) = o;
        // folded aprep: center tap -> inpf hi-only frag (4 channels)
        {
            int rt = r >> 4, kc = c4 >> 5;
            int lp = (r & 15) + ((c4 & 31) >> 3) * 16;
            int i0 = c4 & 7;
            unsigned u0 = (unsigned)bf16c(ctr.x) | ((unsigned)bf16c(ctr.y) << 16);
            unsigned u1 = (unsigned)bf16c(ctr.z) | ((unsigned)bf16c(ctr.w) << 16);
            *(uint2*)(inpf + ((size_t)rt * 4 + kc) * 512 + lp * 8 + i0) = make_uint2(u0, u1);
        }
        #pragma unroll
        for (int cc = 0; cc < 4; ++cc) { s4[cc] += acc[cc]; q4[cc] += acc[cc] * acc[cc]; }
    }

    __shared__ float ls[8][128], lq[8][128];
    #pragma unroll
    for (int cc = 0; cc < 4; ++cc) { ls[wg][c4 + cc] = s4[cc]; lq[wg][c4 + cc] = q4[cc]; }
    __syncthreads();
    if (tid < 128) {
        float s = 0.f, q = 0.f;
        #pragma unroll
        for (int r = 0; r < 8; ++r) { s += ls[r][tid]; q += lq[r][tid]; }
        psum[blk * 128 + tid] = s;
        psq [blk * 128 + tid] = q;
    }
}

// K_pd: merged prep (184 blocks) + dwconv (512 blocks). grid 696.
__global__ __launch_bounds__(256) void k_pd(
    const float* __restrict__ inp, unsigned short* __restrict__ inpf,
    unsigned short* __restrict__ xpad,
    const float* __restrict__ w0, const float* __restrict__ w1,
    const float* __restrict__ w2, const float* __restrict__ w3,
    const float* __restrict__ w4, unsigned short* __restrict__ wb,
    const float* __restrict__ dww, const float* __restrict__ dwb,
    unsigned short* __restrict__ ydwb, float* __restrict__ psum,
    float* __restrict__ psq)
{
    int bid = blockIdx.x;
    if (bid < 184) prep_body(bid, threadIdx.x, xpad, w0, w1, w2, w3, w4, wb);
    else           dwconv_body(bid - 184, threadIdx.x, inp, dww, dwb, ydwb, psum, psq, inpf);
}

// ---------------------------------------------------------------------------
// K2: finalize BN stats -> scale/shift per channel.
// ---------------------------------------------------------------------------
__global__ __launch_bounds__(256) void k_bnstats(
    const float* __restrict__ psum, const float* __restrict__ psq,
    const float* __restrict__ gamma, const float* __restrict__ beta,
    float* __restrict__ sc, float* __restrict__ sh)
{
    int c = blockIdx.x;
    int t = threadIdx.x;
    float s = psum[t * 128 + c] + psum[(t + 256) * 128 + c];
    float q = psq [t * 128 + c] + psq [(t + 256) * 128 + c];
    __shared__ float rs[256], rq[256];
    rs[t] = s; rq[t] = q; __syncthreads();
    for (int off = 128; off > 0; off >>= 1) {
        if (t < off) { rs[t] += rs[t + off]; rq[t] += rq[t + off]; }
        __syncthreads();
    }
    if (t == 0) {
        float mean = rs[0] * (1.0f / 32768.0f);
        float var  = rq[0] * (1.0f / 32768.0f) - mean * mean;
        float scale = gamma[c] * rsqrtf(var + 1e-5f);
        sc[c] = scale;
        sh[c] = beta[c] - mean * scale;
    }
}

// ---------------------------------------------------------------------------
// bngelu body: bf16 ydw -> BN + exact GELU -> x1 hi-only frags.
// ---------------------------------------------------------------------------
__device__ void bngelu_body(
    int bid, int tid,
    const unsigned short* __restrict__ ydwb, const float* __restrict__ sc,
    const float* __restrict__ sh, unsigned short* __restrict__ dst)
{
    int idx = bid * 256 + tid;   // 32768*16
    int r = idx >> 4, k8 = (idx & 15) * 8;
    uint4 yv = *(const uint4*)(ydwb + (size_t)r * 128 + k8);
    const unsigned* cc = (const unsigned*)&yv;
    float t[8];
    #pragma unroll
    for (int j = 0; j < 4; ++j) {
        t[2 * j]     = bfd(cc[j]);
        t[2 * j + 1] = __builtin_bit_cast(float, cc[j] & 0xFFFF0000u);
    }
    float s[8], h[8];
    *(float4*)(s)     = *(const float4*)(sc + k8);
    *(float4*)(s + 4) = *(const float4*)(sc + k8 + 4);
    *(float4*)(h)     = *(const float4*)(sh + k8);
    *(float4*)(h + 4) = *(const float4*)(sh + k8 + 4);
    #pragma unroll
    for (int i = 0; i < 8; ++i) t[i] = gelu_exact(t[i] * s[i] + h[i]);
    uint4 hi = pack8hi(t);
    int rt = r >> 4, kc = k8 >> 5, lp = (r & 15) + ((k8 & 31) >> 3) * 16;
    size_t base = ((size_t)rt * 4 + kc) * 512 + lp * 8;
    *(uint4*)(dst + base) = hi;
}

// ---------------------------------------------------------------------------
// Frag-stream MFMA GEMM body (hi-only). MODE 3: bf16 padded store.
// ---------------------------------------------------------------------------
template<int KDIM, int NT_TOT, int NT_W, int MODE, int NV>
__device__ void fgemm_body(
    int bx, int by, int tid,
    const unsigned short* __restrict__ AF, const unsigned short* __restrict__ WF,
    const float* __restrict__ bias, float* __restrict__ C)
{
    constexpr int KC = KDIM / 32;
    int lane = tid & 63, w = tid >> 6;
    int rt0 = bx * 8 + w * 2;      // 2 rowtiles per wave
    int t0 = by * NT_W;            // n-tile chunk base

    f32x4 acc[2][NT_W];
    #pragma unroll
    for (int rt = 0; rt < 2; ++rt)
        #pragma unroll
        for (int t = 0; t < NT_W; ++t) acc[rt][t] = (f32x4){0.f, 0.f, 0.f, 0.f};

    const bf8_t* Ab0 = (const bf8_t*)AF + (size_t)rt0 * KC * 64 + lane;
    const bf8_t* Ab1 = Ab0 + KC * 64;
    const bf8_t* WHp = (const bf8_t*)WF + lane;

    #pragma unroll
    for (int kc = 0; kc < KC; ++kc) {
        bf8_t a0h = Ab0[kc * 64];
        bf8_t a1h = Ab1[kc * 64];
        #pragma unroll
        for (int t = 0; t < NT_W; ++t) {
            int tg = t0 + t;
            if (tg < NT_TOT) {
                bf8_t wh = WHp[(kc * NT_TOT + tg) * 64];
                acc[0][t] = __builtin_amdgcn_mfma_f32_16x16x32_bf16(wh, a0h, acc[0][t], 0, 0, 0);
                acc[1][t] = __builtin_amdgcn_mfma_f32_16x16x32_bf16(wh, a1h, acc[1][t], 0, 0, 0);
            }
        }
    }

    #pragma unroll
    for (int rt = 0; rt < 2; ++rt) {
        if (MODE == 3) {
            unsigned short* Cp = (unsigned short*)C;
            int m = (rt0 + rt) * 16 + (lane & 15);
            int bb_ = m >> 12, hwm = m & 4095;
            size_t rowb = (((size_t)bb_ * 66 + (hwm >> 6) + 1) * 66 + (hwm & 63) + 1) * 128;
            #pragma unroll
            for (int t = 0; t < NT_W; ++t) {
                int tg = t0 + t;
                int nb = tg * 16 + ((lane >> 4) << 2);
                if (tg < NT_TOT) {
                    float4 bb = *(const float4*)(bias + nb);
                    f32x4 a = acc[rt][t];
                    ushort4 v;
                    v.x = bf16c(a[0] + bb.x); v.y = bf16c(a[1] + bb.y);
                    v.z = bf16c(a[2] + bb.z); v.w = bf16c(a[3] + bb.w);
                    *(ushort4*)(Cp + rowb + nb) = v;
                }
            }
        }
    }
}

// K_bp: merged bngelu (2048 blocks) + proj GEMM (512 blocks, NT_W=4). grid 2560.
__global__ __launch_bounds__(256) void k_bp(
    const unsigned short* __restrict__ ydwb, const float* __restrict__ sc,
    const float* __restrict__ sh, unsigned short* __restrict__ x1f,
    const unsigned short* __restrict__ inpf, const unsigned short* __restrict__ wprojf,
    const float* __restrict__ bproj, unsigned short* __restrict__ xpad)
{
    int bid = blockIdx.x;
    if (bid < 2048) {
        bngelu_body(bid, threadIdx.x, ydwb, sc, sh, x1f);
    } else {
        int pbid = bid - 2048;
        fgemm_body<128, 8, 4, 3, 128>(pbid & 255, pbid >> 8, threadIdx.x,
            inpf, wprojf, bproj, (float*)xpad);
    }
}

// ---------------------------------------------------------------------------
// K6: FUSED offset/mask GEMM + DCNv3 core, v2 (occupancy-restored).
// block = 512 threads (8 waves), 32 positions (= 2 rowtiles). grid 1024.
// ---------------------------------------------------------------------------
__global__ __launch_bounds__(512) void k_dcn(
    const unsigned short* __restrict__ x1f, const unsigned short* __restrict__ womb,
    const float* __restrict__ boff, const float* __restrict__ bmask,
    const unsigned short* __restrict__ xpad, unsigned short* __restrict__ dcnf)
{
    __shared__ unsigned short offs_l[32][148];   // 9.25 KB
    __shared__ unsigned short msk_l[32][76];     // 4.75 KB
    int tid = threadIdx.x;
    int lane = tid & 63, wv = tid >> 6;          // 8 waves
    int rtl = wv & 1, chunk = wv >> 1;           // rowtile-local, 4-tile chunk
    int rt = blockIdx.x * 2 + rtl;

    // ---- phase 1: offs/msk GEMM into LDS ----
    {
        f32x4 acc[4];
        #pragma unroll
        for (int t = 0; t < 4; ++t) acc[t] = (f32x4){0.f, 0.f, 0.f, 0.f};
        const bf8_t* Ab = (const bf8_t*)x1f + (size_t)rt * 4 * 64 + lane;
        const bf8_t* WH = (const bf8_t*)womb + lane;
        #pragma unroll
        for (int kc = 0; kc < 4; ++kc) {
            bf8_t ah = Ab[kc * 64];
            #pragma unroll
            for (int t = 0; t < 4; ++t) {
                int tg = chunk * 4 + t;
                if (tg < 14) {
                    bf8_t wh = WH[(kc * 14 + tg) * 64];
                    acc[t] = __builtin_amdgcn_mfma_f32_16x16x32_bf16(wh, ah, acc[t], 0, 0, 0);
                }
            }
        }
        int m = rtl * 16 + (lane & 15);          // local row 0..31
        #pragma unroll
        for (int t = 0; t < 4; ++t) {
            int tg = chunk * 4 + t;
            if (tg < 14) {
                int nb = tg * 16 + ((lane >> 4) << 2);
                f32x4 a = acc[t];
                if (nb < 144) {
                    float4 bb = *(const float4*)(boff + nb);
                    ushort4 v;
                    v.x = bf16c(a[0] + bb.x); v.y = bf16c(a[1] + bb.y);
                    v.z = bf16c(a[2] + bb.z); v.w = bf16c(a[3] + bb.w);
                    *(ushort4*)(&offs_l[m][nb]) = v;
                } else {
                    int col = nb - 144;
                    if (col + 4 <= 72) {
                        float4 bb = *(const float4*)(bmask + col);
                        ushort4 v;
                        v.x = bf16c(a[0] + bb.x); v.y = bf16c(a[1] + bb.y);
                        v.z = bf16c(a[2] + bb.z); v.w = bf16c(a[3] + bb.w);
                        *(ushort4*)(&msk_l[m][col]) = v;
                    }
                }
            }
        }
    }
    __syncthreads();

    // ---- phase 2: softmax + bilinear gather; thread = (pos, g, half) ----
    int q = tid & 1;
    int g = (tid >> 1) & 7;
    int lpos = tid >> 4;                         // 0..31
    int pos = blockIdx.x * 32 + lpos;
    int b = pos >> 12, hw = pos & 4095, h = hw >> 6, w = hw & 63;

    float e[9];
    float mx = -1e30f;
    #pragma unroll
    for (int p = 0; p < 9; ++p) { e[p] = bfd((unsigned)msk_l[lpos][g * 9 + p]); mx = fmaxf(mx, e[p]); }
    float ssum = 0.f;
    #pragma unroll
    for (int p = 0; p < 9; ++p) { e[p] = __expf(e[p] - mx); ssum += e[p]; }
    float inv = 1.0f / ssum;

    int ch = g * 16 + q * 8;
    const unsigned short* xb = xpad + (size_t)b * 557568 + ch;  // 66*66*128/b

    float acc[8];
    #pragma unroll
    for (int i = 0; i < 8; ++i) acc[i] = 0.f;

    #pragma unroll
    for (int p = 0; p < 9; ++p) {
        unsigned dpair = *(const unsigned*)(&offs_l[lpos][g * 18 + p * 2]);
        float dx = bfd(dpair);
        float dy = __builtin_bit_cast(float, dpair & 0xFFFF0000u);
        float px = (float)(w + (p % 3)) + dx;   // padded-grid coords
        float py = (float)(h + (p / 3)) + dy;
        float x0f = floorf(px), y0f = floorf(py);
        float wx = px - x0f, wy = py - y0f;
        int ix = (int)x0f, iy = (int)y0f;
        int ix0 = max(min(ix, 65), 0),     ix1 = max(min(ix + 1, 65), 0);
        int iy0 = max(min(iy, 65), 0),     iy1 = max(min(iy + 1, 65), 0);
        int r0 = iy0 * 66, r1 = iy1 * 66;

        float mp  = e[p] * inv;
        float w11 = wy * wx * mp;
        float w10 = wy * mp - w11;
        float w01 = wx * mp - w11;
        float w00 = mp - w01 - w10 - w11;

        uint4 s00 = *(const uint4*)(xb + (size_t)(r0 + ix0) * 128);
        uint4 s01 = *(const uint4*)(xb + (size_t)(r0 + ix1) * 128);
        uint4 s10 = *(const uint4*)(xb + (size_t)(r1 + ix0) * 128);
        uint4 s11 = *(const uint4*)(xb + (size_t)(r1 + ix1) * 128);

        ufma(acc, s00, w00);
        ufma(acc, s01, w01);
        ufma(acc, s10, w10);
        ufma(acc, s11, w11);
    }

    // pack 8 channels as one hi-only frag group
    int rto = pos >> 4, kc = ch >> 5;                       // kc = g>>1
    int lp = (pos & 15) + (((g & 1) << 1) + q) * 16;        // ((ch&31)>>3)*16
    size_t fb = ((size_t)rto * 4 + kc) * 512 + (size_t)lp * 8;
    *(uint4*)(dcnf + fb) = pack8hi(acc);
}

// ---------------------------------------------------------------------------
// K7: fused output MLP. block = 512 threads (8 waves) = 2 rowtile-PAIRS.
// ---------------------------------------------------------------------------
__global__ __launch_bounds__(512) void k_mlp(
    const unsigned short* __restrict__ dcnf, const unsigned short* __restrict__ wf1,
    const float* __restrict__ bfc1, const unsigned short* __restrict__ wf2,
    const float* __restrict__ bfc2, float* __restrict__ out)
{
    __shared__ unsigned short hid[4][16][264];   // 4 rowtiles, 33.8 KB
    int tid = threadIdx.x;
    int lane = tid & 63, w = tid >> 6;           // 8 waves
    int pr = w & 1, chunk = w >> 1;              // pair-local, chunk 0..3
    int bp = blockIdx.x * 2 + pr;                // pair id 0..1023
    int rt0 = bp * 2;                            // rowtiles rt0, rt0+1
    int m = lane & 15, hi4 = (lane >> 4) << 2;

    // ---- fc1: hidden tiles chunk*4 .. +3, rowtiles rt0, rt0+1 ----
    f32x4 acc[2][4];
    #pragma unroll
    for (int r = 0; r < 2; ++r)
        #pragma unroll
        for (int t = 0; t < 4; ++t) acc[r][t] = (f32x4){0.f, 0.f, 0.f, 0.f};
    const bf8_t* Ab0 = (const bf8_t*)dcnf + (size_t)rt0 * 4 * 64 + lane;  // KC=4 hi-only
    const bf8_t* Ab1 = Ab0 + 4 * 64;
    const bf8_t* WH1 = (const bf8_t*)wf1 + lane;
    #pragma unroll
    for (int kc = 0; kc < 4; ++kc) {
        bf8_t a0 = Ab0[kc * 64];
        bf8_t a1 = Ab1[kc * 64];
        #pragma unroll
        for (int t = 0; t < 4; ++t) {
            int tg = chunk * 4 + t;
            bf8_t wh = WH1[(kc * 16 + tg) * 64];
            acc[0][t] = __builtin_amdgcn_mfma_f32_16x16x32_bf16(wh, a0, acc[0][t], 0, 0, 0);
            acc[1][t] = __builtin_amdgcn_mfma_f32_16x16x32_bf16(wh, a1, acc[1][t], 0, 0, 0);
        }
    }
    // GELU + bf16 -> LDS
    #pragma unroll
    for (int r = 0; r < 2; ++r) {
        #pragma unroll
        for (int t = 0; t < 4; ++t) {
            int nb = (chunk * 4 + t) * 16 + hi4;
            float4 bb = *(const float4*)(bfc1 + nb);
            ushort4 v;
            v.x = bf16c(gelu_exact(acc[r][t][0] + bb.x));
            v.y = bf16c(gelu_exact(acc[r][t][1] + bb.y));
            v.z = bf16c(gelu_exact(acc[r][t][2] + bb.z));
            v.w = bf16c(gelu_exact(acc[r][t][3] + bb.w));
            *(ushort4*)(&hid[pr * 2 + r][m][nb]) = v;
        }
    }

    __syncthreads();

    // ---- fc2: out tiles chunk*2 .. +1, rowtiles rt0, rt0+1 ----
    f32x4 acc2[2][2];
    #pragma unroll
    for (int r = 0; r < 2; ++r)
        #pragma unroll
        for (int t = 0; t < 2; ++t) acc2[r][t] = (f32x4){0.f, 0.f, 0.f, 0.f};
    const bf8_t* WH2 = (const bf8_t*)wf2 + lane;
    #pragma unroll
    for (int kc = 0; kc < 8; ++kc) {
        bf8_t ah0 = *(const bf8_t*)(&hid[pr * 2 + 0][m][kc * 32 + (lane >> 4) * 8]);
        bf8_t ah1 = *(const bf8_t*)(&hid[pr * 2 + 1][m][kc * 32 + (lane >> 4) * 8]);
        #pragma unroll
        for (int t = 0; t < 2; ++t) {
            int tg = chunk * 2 + t;
            bf8_t wh = WH2[(kc * 8 + tg) * 64];
            acc2[0][t] = __builtin_amdgcn_mfma_f32_16x16x32_bf16(ah0, wh, acc2[0][t], 0, 0, 0);
            acc2[1][t] = __builtin_amdgcn_mfma_f32_16x16x32_bf16(ah1, wh, acc2[1][t], 0, 0, 0);
        }
    }
    // NCHW transposed fp32 store
    #pragma unroll
    for (int r = 0; r < 2; ++r) {
        int m4 = (rt0 + r) * 16 + hi4;
        int b = m4 >> 12, hw = m4 & 4095;
        #pragma unroll
        for (int t = 0; t < 2; ++t) {
            int n = (chunk * 2 + t) * 16 + m;
            float bb = bfc2[n];
            f32x4 a = acc2[r][t];
            float4 v = {a[0] + bb, a[1] + bb, a[2] + bb, a[3] + bb};
            *(float4*)(out + (((size_t)(b * 128 + n)) << 12) + hw) = v;
        }
    }
}

// ---------------------------------------------------------------------------
extern "C" void kernel_launch(void* const* d_in, const int* in_sizes, int n_in,
                              void* d_out, int out_size, void* d_ws, size_t ws_size,
                              hipStream_t stream)
{
    const float* inp   = (const float*)d_in[0];
    const float* wproj = (const float*)d_in[1];
    const float* bproj = (const float*)d_in[2];
    const float* dww   = (const float*)d_in[3];
    const float* dwb   = (const float*)d_in[4];
    const float* gamma = (const float*)d_in[5];
    const float* beta  = (const float*)d_in[6];
    const float* woff  = (const float*)d_in[7];
    const float* boff  = (const float*)d_in[8];
    const float* wmask = (const float*)d_in[9];
    const float* bmask = (const float*)d_in[10];
    const float* wfc1  = (const float*)d_in[11];
    const float* bfc1  = (const float*)d_in[12];
    const float* wfc2  = (const float*)d_in[13];
    const float* bfc2  = (const float*)d_in[14];
    float* out = (float*)d_out;
    float* ws  = (float*)d_ws;

    // xpad (bf16)
    unsigned short* xpad = (unsigned short*)ws;              // 4,460,544 ush [bp..dcn]
    // Region A at ws+9179136: inpf [pd..bp-proj], dcnf [dcn..mlp]
    unsigned short* inpf  = (unsigned short*)(ws + 9179136);   // 4,194,304 ush hi-only
    unsigned short* dcnf  = (unsigned short*)(ws + 9179136);   // 4,194,304 ush hi-only
    unsigned short* x1f   = (unsigned short*)(ws + 13373440);  // 4,194,304 ush hi-only [bp..dcn]
    unsigned short* ydwb  = (unsigned short*)(ws + 15470592);  // 4,194,304 ush bf16 [pd..bp]
    // Rest
    float* psum = ws + 19927040;                         // 65,536 f
    float* psq  = ws + 19992576;                         // 65,536 f
    float* scs  = ws + 20058112;                         // 128 f
    float* shs  = ws + 20058240;                         // 128 f
    unsigned short* wfr = (unsigned short*)(ws + 20058368);  // 176,128 ush

    unsigned short* wproj_f = wfr;            // hi-only, 16384
    unsigned short* womb_f  = wfr + 16384;    // hi-only combined, 28672
    unsigned short* wfc1_f  = wfr + 45056;    // hi(/lo stored), hi consumed
    unsigned short* wfc2_f  = wfr + 110592;   // hi(/lo stored), hi consumed

    k_pd<<<696, 256, 0, stream>>>(inp, inpf, xpad, wproj, woff, wmask, wfc1, wfc2,
                                  wfr, dww, dwb, ydwb, psum, psq);
    k_bnstats<<<128, 256, 0, stream>>>(psum, psq, gamma, beta, scs, shs);
    k_bp<<<2560, 256, 0, stream>>>(ydwb, scs, shs, x1f, inpf, wproj_f, bproj, xpad);
    k_dcn<<<1024, 512, 0, stream>>>(x1f, womb_f, boff, bmask, xpad, dcnf);
    k_mlp<<<512, 512, 0, stream>>>(dcnf, wfc1_f, bfc1, wfc2_f, bfc2, out);
}

// Round 19
// 82.074 us; speedup vs baseline: 1.1051x; 1.0033x over previous
//
#include <hip/hip_runtime.h>
#include <math.h>

#define NPOS  32768      // B*H*W
#define CDIM  128
#define HS    64
#define WSZ   64

typedef __bf16 bf8_t  __attribute__((ext_vector_type(8)));
typedef float  f32x4  __attribute__((ext_vector_type(4)));

__device__ __forceinline__ float gelu_exact(float x) {
    return 0.5f * x * (1.0f + erff(x * 0.70710678118654752f));
}

__device__ __forceinline__ unsigned short bf16c(float v) {
    return __builtin_bit_cast(unsigned short, (__bf16)v);
}

__device__ __forceinline__ uint4 pack8hi(const float* v) {
    unsigned hh[8];
    #pragma unroll
    for (int i = 0; i < 8; ++i) hh[i] = (unsigned)bf16c(v[i]);
    return make_uint4(hh[0] | (hh[1] << 16), hh[2] | (hh[3] << 16),
                      hh[4] | (hh[5] << 16), hh[6] | (hh[7] << 16));
}

__device__ __forceinline__ float bfd(unsigned u) {        // low 16 bits as bf16
    return __builtin_bit_cast(float, u << 16);
}

// unpack uint4 (8 bf16) and fma into acc[8] with weight
__device__ __forceinline__ void ufma(float* acc, uint4 c, float wgt) {
    const unsigned* cc = (const unsigned*)&c;
    #pragma unroll
    for (int j = 0; j < 4; ++j) {
        acc[2 * j]     += __builtin_bit_cast(float, cc[j] << 16) * wgt;
        acc[2 * j + 1] += __builtin_bit_cast(float, cc[j] & 0xFFFF0000u) * wgt;
    }
}

// ---------------------------------------------------------------------------
// A-frag layouts (K=KC*32): hi-only buffers: block(rt,kc) = 512 ush
//  elem: lane*8 + i, lane = (row%16) + ((k%32)/8)*16, i = k%8
// ---------------------------------------------------------------------------

// ---------------------------------------------------------------------------
// prep body: blocks [0,130) border: zero 1-px ring of bf16 xpad
//            [130,184) wprep: weights -> frag bf16
// ---------------------------------------------------------------------------
__device__ void prep_body(
    int bid, int tid,
    unsigned short* __restrict__ xpad,
    const float* __restrict__ w0, const float* __restrict__ w1,
    const float* __restrict__ w2, const float* __restrict__ w3,
    const float* __restrict__ w4, unsigned short* __restrict__ wb)
{
    if (bid < 130) {
        int idx = bid * 256 + tid;         // 2080 cells * 16
        if (idx < 33280) {
            int c8 = (idx & 15) * 8;
            int cell = idx >> 4;
            int b = cell / 260, r = cell % 260;
            int h, w;
            if (r < 66)       { h = 0;  w = r; }
            else if (r < 132) { h = 65; w = r - 66; }
            else { int rr = r - 132; h = 1 + (rr >> 1); w = (rr & 1) * 65; }
            size_t o = (((size_t)b * 66 + h) * 66 + w) * 128 + c8;
            *(uint4*)(xpad + o) = make_uint4(0u, 0u, 0u, 0u);
        }
    } else {
        int sub = (bid - 130) * 4 + (tid >> 6);    // 0..215
        int lane = tid & 63;
        int NT, K, local; unsigned short* out; bool hl; bool comb = false;
        const float* W = nullptr; int N = 0;
        if (sub < 32)       { NT = 8;  K = 128; out = wb;          local = sub;       hl = false; W = w0; N = 128; }
        else if (sub < 88)  { NT = 14; K = 128; out = wb + 16384;  local = sub - 32;  hl = false; comb = true; }
        else if (sub < 152) { NT = 16; K = 128; out = wb + 45056;  local = sub - 88;  hl = true;  W = w3; N = 256; }
        else                { NT = 8;  K = 256; out = wb + 110592; local = sub - 152; hl = true;  W = w4; N = 128; }
        int KC = K / 32;
        int unit = KC * NT * 512;
        int kc = local / NT, t = local % NT;
        int nt = t * 16 + (lane & 15);
        const float* Wp = W; int n = nt, Nv = N;
        if (comb) {
            if (t < 9) { Wp = w1; n = nt;       Nv = 144; }
            else       { Wp = w2; n = nt - 144; Nv = 72;  }
        }
        int kb = kc * 32 + (lane >> 4) * 8;
        size_t base = ((size_t)local * 64 + lane) * 8;
        #pragma unroll
        for (int i = 0; i < 8; ++i) {
            float v = (n < Nv) ? Wp[(size_t)n * K + kb + i] : 0.f;
            __bf16 h = (__bf16)v;
            out[base + i] = __builtin_bit_cast(unsigned short, h);
            if (hl) {
                __bf16 l = (__bf16)(v - (float)h);
                out[unit + base + i] = __builtin_bit_cast(unsigned short, l);
            }
        }
    }
}

// ---------------------------------------------------------------------------
// dwconv body: depthwise 3x3 (NHWC) -> bf16 ydw + partial BN sums (fp32)
//              + center-tap -> inpf hi-only frags (folded aprep)
// ---------------------------------------------------------------------------
__device__ void dwconv_body(
    int blk, int tid,
    const float* __restrict__ inp, const float* __restrict__ dww,
    const float* __restrict__ dwb, unsigned short* __restrict__ ydwb,
    float* __restrict__ psum, float* __restrict__ psq,
    unsigned short* __restrict__ inpf)
{
    int b = blk >> 6, h = blk & 63;
    int c4 = (tid & 31) * 4;
    int wg = tid >> 5;               // 0..7

    float wreg[4][9];
    #pragma unroll
    for (int cc = 0; cc < 4; ++cc)
        #pragma unroll
        for (int p = 0; p < 9; ++p)
            wreg[cc][p] = dww[(c4 + cc) * 9 + p];
    float bia[4];
    #pragma unroll
    for (int cc = 0; cc < 4; ++cc) bia[cc] = dwb[c4 + cc];

    float s4[4] = {0,0,0,0}, q4[4] = {0,0,0,0};
    const float* ibase = inp + (size_t)(b << 12) * CDIM;

    for (int i = 0; i < 8; ++i) {
        int w = wg + i * 8;
        float acc[4] = {bia[0], bia[1], bia[2], bia[3]};
        float4 ctr;
        #pragma unroll
        for (int ky = 0; ky < 3; ++ky) {
            int yy = h + ky - 1;
            if (yy < 0 || yy >= HS) continue;
            #pragma unroll
            for (int kx = 0; kx < 3; ++kx) {
                int xx = w + kx - 1;
                if (xx < 0 || xx >= WSZ) continue;
                float4 v = *(const float4*)(ibase + (size_t)(yy * 64 + xx) * CDIM + c4);
                if (ky == 1 && kx == 1) ctr = v;
                int p = ky * 3 + kx;
                acc[0] += v.x * wreg[0][p];
                acc[1] += v.y * wreg[1][p];
                acc[2] += v.z * wreg[2][p];
                acc[3] += v.w * wreg[3][p];
            }
        }
        int r = (b << 12) + h * 64 + w;
        ushort4 o;
        o.x = bf16c(acc[0]); o.y = bf16c(acc[1]);
        o.z = bf16c(acc[2]); o.w = bf16c(acc[3]);
        *(ushort4*)(ydwb + (size_t)r * CDIM + c4) = o;
        // folded aprep: center tap -> inpf hi-only frag (4 channels)
        {
            int rt = r >> 4, kc = c4 >> 5;
            int lp = (r & 15) + ((c4 & 31) >> 3) * 16;
            int i0 = c4 & 7;
            unsigned u0 = (unsigned)bf16c(ctr.x) | ((unsigned)bf16c(ctr.y) << 16);
            unsigned u1 = (unsigned)bf16c(ctr.z) | ((unsigned)bf16c(ctr.w) << 16);
            *(uint2*)(inpf + ((size_t)rt * 4 + kc) * 512 + lp * 8 + i0) = make_uint2(u0, u1);
        }
        #pragma unroll
        for (int cc = 0; cc < 4; ++cc) { s4[cc] += acc[cc]; q4[cc] += acc[cc] * acc[cc]; }
    }

    __shared__ float ls[8][128], lq[8][128];
    #pragma unroll
    for (int cc = 0; cc < 4; ++cc) { ls[wg][c4 + cc] = s4[cc]; lq[wg][c4 + cc] = q4[cc]; }
    __syncthreads();
    if (tid < 128) {
        float s = 0.f, q = 0.f;
        #pragma unroll
        for (int r = 0; r < 8; ++r) { s += ls[r][tid]; q += lq[r][tid]; }
        psum[blk * 128 + tid] = s;
        psq [blk * 128 + tid] = q;
    }
}

// K_pd: merged prep (184 blocks) + dwconv (512 blocks). grid 696.
__global__ __launch_bounds__(256) void k_pd(
    const float* __restrict__ inp, unsigned short* __restrict__ inpf,
    unsigned short* __restrict__ xpad,
    const float* __restrict__ w0, const float* __restrict__ w1,
    const float* __restrict__ w2, const float* __restrict__ w3,
    const float* __restrict__ w4, unsigned short* __restrict__ wb,
    const float* __restrict__ dww, const float* __restrict__ dwb,
    unsigned short* __restrict__ ydwb, float* __restrict__ psum,
    float* __restrict__ psq)
{
    int bid = blockIdx.x;
    if (bid < 184) prep_body(bid, threadIdx.x, xpad, w0, w1, w2, w3, w4, wb);
    else           dwconv_body(bid - 184, threadIdx.x, inp, dww, dwb, ydwb, psum, psq, inpf);
}

// ---------------------------------------------------------------------------
// K2: finalize BN stats -> scale/shift per channel.
// ---------------------------------------------------------------------------
__global__ __launch_bounds__(256) void k_bnstats(
    const float* __restrict__ psum, const float* __restrict__ psq,
    const float* __restrict__ gamma, const float* __restrict__ beta,
    float* __restrict__ sc, float* __restrict__ sh)
{
    int c = blockIdx.x;
    int t = threadIdx.x;
    float s = psum[t * 128 + c] + psum[(t + 256) * 128 + c];
    float q = psq [t * 128 + c] + psq [(t + 256) * 128 + c];
    __shared__ float rs[256], rq[256];
    rs[t] = s; rq[t] = q; __syncthreads();
    for (int off = 128; off > 0; off >>= 1) {
        if (t < off) { rs[t] += rs[t + off]; rq[t] += rq[t + off]; }
        __syncthreads();
    }
    if (t == 0) {
        float mean = rs[0] * (1.0f / 32768.0f);
        float var  = rq[0] * (1.0f / 32768.0f) - mean * mean;
        float scale = gamma[c] * rsqrtf(var + 1e-5f);
        sc[c] = scale;
        sh[c] = beta[c] - mean * scale;
    }
}

// ---------------------------------------------------------------------------
// bngelu body: bf16 ydw -> BN + exact GELU -> x1 hi-only frags.
// ---------------------------------------------------------------------------
__device__ void bngelu_body(
    int bid, int tid,
    const unsigned short* __restrict__ ydwb, const float* __restrict__ sc,
    const float* __restrict__ sh, unsigned short* __restrict__ dst)
{
    int idx = bid * 256 + tid;   // 32768*16
    int r = idx >> 4, k8 = (idx & 15) * 8;
    uint4 yv = *(const uint4*)(ydwb + (size_t)r * 128 + k8);
    const unsigned* cc = (const unsigned*)&yv;
    float t[8];
    #pragma unroll
    for (int j = 0; j < 4; ++j) {
        t[2 * j]     = bfd(cc[j]);
        t[2 * j + 1] = __builtin_bit_cast(float, cc[j] & 0xFFFF0000u);
    }
    float s[8], h[8];
    *(float4*)(s)     = *(const float4*)(sc + k8);
    *(float4*)(s + 4) = *(const float4*)(sc + k8 + 4);
    *(float4*)(h)     = *(const float4*)(sh + k8);
    *(float4*)(h + 4) = *(const float4*)(sh + k8 + 4);
    #pragma unroll
    for (int i = 0; i < 8; ++i) t[i] = gelu_exact(t[i] * s[i] + h[i]);
    uint4 hi = pack8hi(t);
    int rt = r >> 4, kc = k8 >> 5, lp = (r & 15) + ((k8 & 31) >> 3) * 16;
    size_t base = ((size_t)rt * 4 + kc) * 512 + lp * 8;
    *(uint4*)(dst + base) = hi;
}

// ---------------------------------------------------------------------------
// Frag-stream MFMA GEMM body (hi-only). MODE 3: bf16 padded store.
// ---------------------------------------------------------------------------
template<int KDIM, int NT_TOT, int NT_W, int MODE, int NV>
__device__ void fgemm_body(
    int bx, int by, int tid,
    const unsigned short* __restrict__ AF, const unsigned short* __restrict__ WF,
    const float* __restrict__ bias, float* __restrict__ C)
{
    constexpr int KC = KDIM / 32;
    int lane = tid & 63, w = tid >> 6;
    int rt0 = bx * 8 + w * 2;      // 2 rowtiles per wave
    int t0 = by * NT_W;            // n-tile chunk base

    f32x4 acc[2][NT_W];
    #pragma unroll
    for (int rt = 0; rt < 2; ++rt)
        #pragma unroll
        for (int t = 0; t < NT_W; ++t) acc[rt][t] = (f32x4){0.f, 0.f, 0.f, 0.f};

    const bf8_t* Ab0 = (const bf8_t*)AF + (size_t)rt0 * KC * 64 + lane;
    const bf8_t* Ab1 = Ab0 + KC * 64;
    const bf8_t* WHp = (const bf8_t*)WF + lane;

    #pragma unroll
    for (int kc = 0; kc < KC; ++kc) {
        bf8_t a0h = Ab0[kc * 64];
        bf8_t a1h = Ab1[kc * 64];
        #pragma unroll
        for (int t = 0; t < NT_W; ++t) {
            int tg = t0 + t;
            if (tg < NT_TOT) {
                bf8_t wh = WHp[(kc * NT_TOT + tg) * 64];
                acc[0][t] = __builtin_amdgcn_mfma_f32_16x16x32_bf16(wh, a0h, acc[0][t], 0, 0, 0);
                acc[1][t] = __builtin_amdgcn_mfma_f32_16x16x32_bf16(wh, a1h, acc[1][t], 0, 0, 0);
            }
        }
    }

    #pragma unroll
    for (int rt = 0; rt < 2; ++rt) {
        if (MODE == 3) {
            unsigned short* Cp = (unsigned short*)C;
            int m = (rt0 + rt) * 16 + (lane & 15);
            int bb_ = m >> 12, hwm = m & 4095;
            size_t rowb = (((size_t)bb_ * 66 + (hwm >> 6) + 1) * 66 + (hwm & 63) + 1) * 128;
            #pragma unroll
            for (int t = 0; t < NT_W; ++t) {
                int tg = t0 + t;
                int nb = tg * 16 + ((lane >> 4) << 2);
                if (tg < NT_TOT) {
                    float4 bb = *(const float4*)(bias + nb);
                    f32x4 a = acc[rt][t];
                    ushort4 v;
                    v.x = bf16c(a[0] + bb.x); v.y = bf16c(a[1] + bb.y);
                    v.z = bf16c(a[2] + bb.z); v.w = bf16c(a[3] + bb.w);
                    *(ushort4*)(Cp + rowb + nb) = v;
                }
            }
        }
    }
}

// K_bp: merged bngelu (2048 blocks) + proj GEMM (512 blocks, NT_W=4). grid 2560.
__global__ __launch_bounds__(256) void k_bp(
    const unsigned short* __restrict__ ydwb, const float* __restrict__ sc,
    const float* __restrict__ sh, unsigned short* __restrict__ x1f,
    const unsigned short* __restrict__ inpf, const unsigned short* __restrict__ wprojf,
    const float* __restrict__ bproj, unsigned short* __restrict__ xpad)
{
    int bid = blockIdx.x;
    if (bid < 2048) {
        bngelu_body(bid, threadIdx.x, ydwb, sc, sh, x1f);
    } else {
        int pbid = bid - 2048;
        fgemm_body<128, 8, 4, 3, 128>(pbid & 255, pbid >> 8, threadIdx.x,
            inpf, wprojf, bproj, (float*)xpad);
    }
}

// ---------------------------------------------------------------------------
// K6: FUSED offset/mask GEMM + DCNv3 core, v3 (+XCD-aware block swizzle).
// block = 512 threads (8 waves), 32 positions (= 2 rowtiles). grid 1024.
// Swizzle bid = (bid0&7)*128 + bid0>>3: if XCD = bid0%8, each XCD serves
// exactly one batch (xpad slice 1.1 MB << 4 MB L2) -> gather L2-resident.
// Bijective (1024 % 8 == 0); performance-only, no correctness dependence.
// ---------------------------------------------------------------------------
__global__ __launch_bounds__(512) void k_dcn(
    const unsigned short* __restrict__ x1f, const unsigned short* __restrict__ womb,
    const float* __restrict__ boff, const float* __restrict__ bmask,
    const unsigned short* __restrict__ xpad, unsigned short* __restrict__ dcnf)
{
    __shared__ unsigned short offs_l[32][148];   // 9.25 KB
    __shared__ unsigned short msk_l[32][76];     // 4.75 KB
    int bid = ((blockIdx.x & 7) << 7) + (blockIdx.x >> 3);   // XCD swizzle
    int tid = threadIdx.x;
    int lane = tid & 63, wv = tid >> 6;          // 8 waves
    int rtl = wv & 1, chunk = wv >> 1;           // rowtile-local, 4-tile chunk
    int rt = bid * 2 + rtl;

    // ---- phase 1: offs/msk GEMM into LDS ----
    {
        f32x4 acc[4];
        #pragma unroll
        for (int t = 0; t < 4; ++t) acc[t] = (f32x4){0.f, 0.f, 0.f, 0.f};
        const bf8_t* Ab = (const bf8_t*)x1f + (size_t)rt * 4 * 64 + lane;
        const bf8_t* WH = (const bf8_t*)womb + lane;
        #pragma unroll
        for (int kc = 0; kc < 4; ++kc) {
            bf8_t ah = Ab[kc * 64];
            #pragma unroll
            for (int t = 0; t < 4; ++t) {
                int tg = chunk * 4 + t;
                if (tg < 14) {
                    bf8_t wh = WH[(kc * 14 + tg) * 64];
                    acc[t] = __builtin_amdgcn_mfma_f32_16x16x32_bf16(wh, ah, acc[t], 0, 0, 0);
                }
            }
        }
        int m = rtl * 16 + (lane & 15);          // local row 0..31
        #pragma unroll
        for (int t = 0; t < 4; ++t) {
            int tg = chunk * 4 + t;
            if (tg < 14) {
                int nb = tg * 16 + ((lane >> 4) << 2);
                f32x4 a = acc[t];
                if (nb < 144) {
                    float4 bb = *(const float4*)(boff + nb);
                    ushort4 v;
                    v.x = bf16c(a[0] + bb.x); v.y = bf16c(a[1] + bb.y);
                    v.z = bf16c(a[2] + bb.z); v.w = bf16c(a[3] + bb.w);
                    *(ushort4*)(&offs_l[m][nb]) = v;
                } else {
                    int col = nb - 144;
                    if (col + 4 <= 72) {
                        float4 bb = *(const float4*)(bmask + col);
                        ushort4 v;
                        v.x = bf16c(a[0] + bb.x); v.y = bf16c(a[1] + bb.y);
                        v.z = bf16c(a[2] + bb.z); v.w = bf16c(a[3] + bb.w);
                        *(ushort4*)(&msk_l[m][col]) = v;
                    }
                }
            }
        }
    }
    __syncthreads();

    // ---- phase 2: softmax + bilinear gather; thread = (pos, g, half) ----
    int q = tid & 1;
    int g = (tid >> 1) & 7;
    int lpos = tid >> 4;                         // 0..31
    int pos = bid * 32 + lpos;
    int b = pos >> 12, hw = pos & 4095, h = hw >> 6, w = hw & 63;

    float e[9];
    float mx = -1e30f;
    #pragma unroll
    for (int p = 0; p < 9; ++p) { e[p] = bfd((unsigned)msk_l[lpos][g * 9 + p]); mx = fmaxf(mx, e[p]); }
    float ssum = 0.f;
    #pragma unroll
    for (int p = 0; p < 9; ++p) { e[p] = __expf(e[p] - mx); ssum += e[p]; }
    float inv = 1.0f / ssum;

    int ch = g * 16 + q * 8;
    const unsigned short* xb = xpad + (size_t)b * 557568 + ch;  // 66*66*128/b

    float acc[8];
    #pragma unroll
    for (int i = 0; i < 8; ++i) acc[i] = 0.f;

    #pragma unroll
    for (int p = 0; p < 9; ++p) {
        unsigned dpair = *(const unsigned*)(&offs_l[lpos][g * 18 + p * 2]);
        float dx = bfd(dpair);
        float dy = __builtin_bit_cast(float, dpair & 0xFFFF0000u);
        float px = (float)(w + (p % 3)) + dx;   // padded-grid coords
        float py = (float)(h + (p / 3)) + dy;
        float x0f = floorf(px), y0f = floorf(py);
        float wx = px - x0f, wy = py - y0f;
        int ix = (int)x0f, iy = (int)y0f;
        int ix0 = max(min(ix, 65), 0),     ix1 = max(min(ix + 1, 65), 0);
        int iy0 = max(min(iy, 65), 0),     iy1 = max(min(iy + 1, 65), 0);
        int r0 = iy0 * 66, r1 = iy1 * 66;

        float mp  = e[p] * inv;
        float w11 = wy * wx * mp;
        float w10 = wy * mp - w11;
        float w01 = wx * mp - w11;
        float w00 = mp - w01 - w10 - w11;

        uint4 s00 = *(const uint4*)(xb + (size_t)(r0 + ix0) * 128);
        uint4 s01 = *(const uint4*)(xb + (size_t)(r0 + ix1) * 128);
        uint4 s10 = *(const uint4*)(xb + (size_t)(r1 + ix0) * 128);
        uint4 s11 = *(const uint4*)(xb + (size_t)(r1 + ix1) * 128);

        ufma(acc, s00, w00);
        ufma(acc, s01, w01);
        ufma(acc, s10, w10);
        ufma(acc, s11, w11);
    }

    // pack 8 channels as one hi-only frag group
    int rto = pos >> 4, kc = ch >> 5;                       // kc = g>>1
    int lp = (pos & 15) + (((g & 1) << 1) + q) * 16;        // ((ch&31)>>3)*16
    size_t fb = ((size_t)rto * 4 + kc) * 512 + (size_t)lp * 8;
    *(uint4*)(dcnf + fb) = pack8hi(acc);
}

// ---------------------------------------------------------------------------
// K7: fused output MLP. block = 512 threads (8 waves) = 2 rowtile-PAIRS.
// ---------------------------------------------------------------------------
__global__ __launch_bounds__(512) void k_mlp(
    const unsigned short* __restrict__ dcnf, const unsigned short* __restrict__ wf1,
    const float* __restrict__ bfc1, const unsigned short* __restrict__ wf2,
    const float* __restrict__ bfc2, float* __restrict__ out)
{
    __shared__ unsigned short hid[4][16][264];   // 4 rowtiles, 33.8 KB
    int tid = threadIdx.x;
    int lane = tid & 63, w = tid >> 6;           // 8 waves
    int pr = w & 1, chunk = w >> 1;              // pair-local, chunk 0..3
    int bp = blockIdx.x * 2 + pr;                // pair id 0..1023
    int rt0 = bp * 2;                            // rowtiles rt0, rt0+1
    int m = lane & 15, hi4 = (lane >> 4) << 2;

    // ---- fc1: hidden tiles chunk*4 .. +3, rowtiles rt0, rt0+1 ----
    f32x4 acc[2][4];
    #pragma unroll
    for (int r = 0; r < 2; ++r)
        #pragma unroll
        for (int t = 0; t < 4; ++t) acc[r][t] = (f32x4){0.f, 0.f, 0.f, 0.f};
    const bf8_t* Ab0 = (const bf8_t*)dcnf + (size_t)rt0 * 4 * 64 + lane;  // KC=4 hi-only
    const bf8_t* Ab1 = Ab0 + 4 * 64;
    const bf8_t* WH1 = (const bf8_t*)wf1 + lane;
    #pragma unroll
    for (int kc = 0; kc < 4; ++kc) {
        bf8_t a0 = Ab0[kc * 64];
        bf8_t a1 = Ab1[kc * 64];
        #pragma unroll
        for (int t = 0; t < 4; ++t) {
            int tg = chunk * 4 + t;
            bf8_t wh = WH1[(kc * 16 + tg) * 64];
            acc[0][t] = __builtin_amdgcn_mfma_f32_16x16x32_bf16(wh, a0, acc[0][t], 0, 0, 0);
            acc[1][t] = __builtin_amdgcn_mfma_f32_16x16x32_bf16(wh, a1, acc[1][t], 0, 0, 0);
        }
    }
    // GELU + bf16 -> LDS
    #pragma unroll
    for (int r = 0; r < 2; ++r) {
        #pragma unroll
        for (int t = 0; t < 4; ++t) {
            int nb = (chunk * 4 + t) * 16 + hi4;
            float4 bb = *(const float4*)(bfc1 + nb);
            ushort4 v;
            v.x = bf16c(gelu_exact(acc[r][t][0] + bb.x));
            v.y = bf16c(gelu_exact(acc[r][t][1] + bb.y));
            v.z = bf16c(gelu_exact(acc[r][t][2] + bb.z));
            v.w = bf16c(gelu_exact(acc[r][t][3] + bb.w));
            *(ushort4*)(&hid[pr * 2 + r][m][nb]) = v;
        }
    }

    __syncthreads();

    // ---- fc2: out tiles chunk*2 .. +1, rowtiles rt0, rt0+1 ----
    f32x4 acc2[2][2];
    #pragma unroll
    for (int r = 0; r < 2; ++r)
        #pragma unroll
        for (int t = 0; t < 2; ++t) acc2[r][t] = (f32x4){0.f, 0.f, 0.f, 0.f};
    const bf8_t* WH2 = (const bf8_t*)wf2 + lane;
    #pragma unroll
    for (int kc = 0; kc < 8; ++kc) {
        bf8_t ah0 = *(const bf8_t*)(&hid[pr * 2 + 0][m][kc * 32 + (lane >> 4) * 8]);
        bf8_t ah1 = *(const bf8_t*)(&hid[pr * 2 + 1][m][kc * 32 + (lane >> 4) * 8]);
        #pragma unroll
        for (int t = 0; t < 2; ++t) {
            int tg = chunk * 2 + t;
            bf8_t wh = WH2[(kc * 8 + tg) * 64];
            acc2[0][t] = __builtin_amdgcn_mfma_f32_16x16x32_bf16(ah0, wh, acc2[0][t], 0, 0, 0);
            acc2[1][t] = __builtin_amdgcn_mfma_f32_16x16x32_bf16(ah1, wh, acc2[1][t], 0, 0, 0);
        }
    }
    // NCHW transposed fp32 store
    #pragma unroll
    for (int r = 0; r < 2; ++r) {
        int m4 = (rt0 + r) * 16 + hi4;
        int b = m4 >> 12, hw = m4 & 4095;
        #pragma unroll
        for (int t = 0; t < 2; ++t) {
            int n = (chunk * 2 + t) * 16 + m;
            float bb = bfc2[n];
            f32x4 a = acc2[r][t];
            float4 v = {a[0] + bb, a[1] + bb, a[2] + bb, a[3] + bb};
            *(float4*)(out + (((size_t)(b * 128 + n)) << 12) + hw) = v;
        }
    }
}

// ---------------------------------------------------------------------------
extern "C" void kernel_launch(void* const* d_in, const int* in_sizes, int n_in,
                              void* d_out, int out_size, void* d_ws, size_t ws_size,
                              hipStream_t stream)
{
    const float* inp   = (const float*)d_in[0];
    const float* wproj = (const float*)d_in[1];
    const float* bproj = (const float*)d_in[2];
    const float* dww   = (const float*)d_in[3];
    const float* dwb   = (const float*)d_in[4];
    const float* gamma = (const float*)d_in[5];
    const float* beta  = (const float*)d_in[6];
    const float* woff  = (const float*)d_in[7];
    const float* boff  = (const float*)d_in[8];
    const float* wmask = (const float*)d_in[9];
    const float* bmask = (const float*)d_in[10];
    const float* wfc1  = (const float*)d_in[11];
    const float* bfc1  = (const float*)d_in[12];
    const float* wfc2  = (const float*)d_in[13];
    const float* bfc2  = (const float*)d_in[14];
    float* out = (float*)d_out;
    float* ws  = (float*)d_ws;

    // xpad (bf16)
    unsigned short* xpad = (unsigned short*)ws;              // 4,460,544 ush [bp..dcn]
    // Region A at ws+9179136: inpf [pd..bp-proj], dcnf [dcn..mlp]
    unsigned short* inpf  = (unsigned short*)(ws + 9179136);   // 4,194,304 ush hi-only
    unsigned short* dcnf  = (unsigned short*)(ws + 9179136);   // 4,194,304 ush hi-only
    unsigned short* x1f   = (unsigned short*)(ws + 13373440);  // 4,194,304 ush hi-only [bp..dcn]
    unsigned short* ydwb  = (unsigned short*)(ws + 15470592);  // 4,194,304 ush bf16 [pd..bp]
    // Rest
    float* psum = ws + 19927040;                         // 65,536 f
    float* psq  = ws + 19992576;                         // 65,536 f
    float* scs  = ws + 20058112;                         // 128 f
    float* shs  = ws + 20058240;                         // 128 f
    unsigned short* wfr = (unsigned short*)(ws + 20058368);  // 176,128 ush

    unsigned short* wproj_f = wfr;            // hi-only, 16384
    unsigned short* womb_f  = wfr + 16384;    // hi-only combined, 28672
    unsigned short* wfc1_f  = wfr + 45056;    // hi(/lo stored), hi consumed
    unsigned short* wfc2_f  = wfr + 110592;   // hi(/lo stored), hi consumed

    k_pd<<<696, 256, 0, stream>>>(inp, inpf, xpad, wproj, woff, wmask, wfc1, wfc2,
                                  wfr, dww, dwb, ydwb, psum, psq);
    k_bnstats<<<128, 256, 0, stream>>>(psum, psq, gamma, beta, scs, shs);
    k_bp<<<2560, 256, 0, stream>>>(ydwb, scs, shs, x1f, inpf, wproj_f, bproj, xpad);
    k_dcn<<<1024, 512, 0, stream>>>(x1f, womb_f, boff, bmask, xpad, dcnf);
    k_mlp<<<512, 512, 0, stream>>>(dcnf, wfc1_f, bfc1, wfc2_f, bfc2, out);
}